// Round 5
// baseline (87.071 us; speedup 1.0000x reference)
//
#include <hip/hip_runtime.h>

typedef float v2f __attribute__((ext_vector_type(2)));

constexpr int NQ = 4;
constexpr int DIM = 16;          // 2^NQ
constexpr float MARGIN = 0.3f;
constexpr float INV2PI = 0.15915494309189535f;

__device__ __forceinline__ v2f mk2(float x, float y) { v2f r; r.x = x; r.y = y; return r; }

// complex multiply a*b where bs = {-b.y, b.x} is precomputed.
__device__ __forceinline__ v2f cmul_pre(v2f a, v2f b, v2f bs) {
  return a.xx * b + a.yy * bs;
}

__device__ __forceinline__ void sincos_hw(float rev, float& s, float& c) {
  s = __builtin_amdgcn_sinf(rev);   // input in revolutions
  c = __builtin_amdgcn_cosf(rev);
}

// CNOT ladder CNOT(q,q+1), q=0..2; qubit q == flat bit (3-q). Free permutation.
__device__ __forceinline__ void cnot_ladder(v2f s[DIM]) {
#pragma unroll
  for (int q = 0; q < NQ - 1; ++q) {
    const int pc = 1 << (NQ - 1 - q);
    const int pt = 1 << (NQ - 2 - q);
#pragma unroll
    for (int i = 0; i < DIM; ++i) {
      if ((i & pc) && !(i & pt)) {
        const int j = i | pt;
        v2f t = s[i]; s[i] = s[j]; s[j] = t;
      }
    }
  }
}

// Layer-1 product state (RZ as diag(1,e^{i z}), global phase dropped) + CNOT
// ladder + layer-2 RY butterflies. Final RZ layer handled by caller (merged);
// final CNOT ladder cancels in the overlap.
__device__ __forceinline__ void sim_core(const float ry[8], const float rz[8], v2f s[DIM]) {
  float c0[NQ]; v2f p1[NQ], p1s[NQ];
#pragma unroll
  for (int q = 0; q < NQ; ++q) {
    float sy, cy; sincos_hw(ry[q] * (0.5f * INV2PI), sy, cy);
    float sz, cz; sincos_hw(rz[q] * INV2PI, sz, cz);
    c0[q]  = cy;
    p1[q]  = mk2(sy * cz, sy * sz);
    p1s[q] = mk2(-p1[q].y, p1[q].x);
  }
  // tensor-product tree; qubit q is flat bit (3-q)
  v2f t2[4];
  t2[0] = mk2(c0[0] * c0[1], 0.0f);
  t2[1] = c0[0] * p1[1];
  t2[2] = c0[1] * p1[0];
  t2[3] = cmul_pre(p1[0], p1[1], p1s[1]);
  v2f t3[8];
#pragma unroll
  for (int k = 0; k < 4; ++k) {
    t3[2*k]   = t2[k] * c0[2];
    t3[2*k+1] = cmul_pre(t2[k], p1[2], p1s[2]);
  }
#pragma unroll
  for (int k = 0; k < 8; ++k) {
    s[2*k]   = t3[k] * c0[3];
    s[2*k+1] = cmul_pre(t3[k], p1[3], p1s[3]);
  }

  cnot_ladder(s);

  // layer-2 RY butterflies
#pragma unroll
  for (int q = 0; q < NQ; ++q) {
    const int bit = 1 << (NQ - 1 - q);
    float sy, cy; sincos_hw(ry[4 + q] * (0.5f * INV2PI), sy, cy);
#pragma unroll
    for (int i = 0; i < DIM; ++i) {
      if (i & bit) continue;
      const int j = i | bit;
      const v2f a0 = s[i], a1 = s[j];
      s[i] = cy * a0 - sy * a1;
      s[j] = sy * a0 + cy * a1;
    }
  }
}

// Merged final RZ (delta angles dz[q] = z[q] - za[q]) then |<a|x>|^2.
__device__ __forceinline__ float fid_with_dz(const v2f a[DIM], v2f x[DIM], const float dz[NQ]) {
#pragma unroll
  for (int q = 0; q < NQ; ++q) {
    const int bit = 1 << (NQ - 1 - q);
    float sz, cz; sincos_hw(dz[q] * INV2PI, sz, cz);
    const v2f ph  = mk2(cz, sz);
    const v2f phs = mk2(-sz, cz);
#pragma unroll
    for (int i = 0; i < DIM; ++i) {
      if (i & bit) x[i] = cmul_pre(x[i], ph, phs);
    }
  }
  v2f ov1 = mk2(0.f, 0.f), ov2 = mk2(0.f, 0.f);
#pragma unroll
  for (int i = 0; i < DIM; ++i) {
    ov1 += a[i].xx * x[i];      // {Σ ar*xr, Σ ar*xi}
    ov2 += a[i].yy * x[i].yx;   // {Σ ai*xi, Σ ai*xr}
  }
  const float ovr = ov1.x + ov2.x;
  const float ovi = ov1.y - ov2.y;
  return ovr * ovr + ovi * ovi;
}

__device__ __forceinline__ void load8(const float* __restrict__ p, int b, float a[8]) {
  const float4* v = reinterpret_cast<const float4*>(p) + (size_t)b * 2;
  float4 x0 = v[0], x1 = v[1];
  a[0]=x0.x; a[1]=x0.y; a[2]=x0.z; a[3]=x0.w;
  a[4]=x1.x; a[5]=x1.y; a[6]=x1.z; a[7]=x1.w;
}

__global__ __launch_bounds__(256, 1) void triplet_fused(
    const float* __restrict__ a_ry, const float* __restrict__ a_rz,
    const float* __restrict__ p_ry, const float* __restrict__ p_rz,
    const float* __restrict__ n_ry, const float* __restrict__ n_rz,
    float* __restrict__ partials, unsigned* __restrict__ counter,
    float* __restrict__ out, int batch) {
  const int b = blockIdx.x * blockDim.x + threadIdx.x;

  float loss = 0.0f;
  if (b < batch) {
    float ry[8], rz[8], arz2[NQ];

    // anchor (final RZ merged into the dots, final CNOT ladder cancelled)
    load8(a_ry, b, ry); load8(a_rz, b, rz);
#pragma unroll
    for (int q = 0; q < NQ; ++q) arz2[q] = rz[4 + q];
    v2f as[DIM];
    sim_core(ry, rz, as);

    // positive
    load8(p_ry, b, ry); load8(p_rz, b, rz);
    v2f xs[DIM];
    sim_core(ry, rz, xs);
    float dz[NQ];
#pragma unroll
    for (int q = 0; q < NQ; ++q) dz[q] = rz[4 + q] - arz2[q];
    const float fid_pos = fid_with_dz(as, xs, dz);

    // negative (reuse xs)
    load8(n_ry, b, ry); load8(n_rz, b, rz);
    sim_core(ry, rz, xs);
#pragma unroll
    for (int q = 0; q < NQ; ++q) dz[q] = rz[4 + q] - arz2[q];
    const float fid_neg = fid_with_dz(as, xs, dz);

    loss = fmaxf(MARGIN - fid_pos + fid_neg, 0.0f);
  }

  // wave (64) reduce, then LDS across the 4 waves
#pragma unroll
  for (int off = 32; off >= 1; off >>= 1)
    loss += __shfl_down(loss, off, 64);

  __shared__ float wsum[4];
  const int lane = threadIdx.x & 63;
  const int wid  = threadIdx.x >> 6;
  if (lane == 0) wsum[wid] = loss;
  __syncthreads();

  __shared__ bool amLast;
  if (threadIdx.x == 0) {
    partials[blockIdx.x] = wsum[0] + wsum[1] + wsum[2] + wsum[3];
    __threadfence();                        // release partial
    unsigned old = atomicAdd(counter, 1u);  // device-scope
    amLast = (old == gridDim.x - 1);
  }
  __syncthreads();

  if (amLast) {
    __threadfence();                        // acquire all partials
    float s = 0.0f;
    for (int i = threadIdx.x; i < (int)gridDim.x; i += 256) s += partials[i];
#pragma unroll
    for (int off = 32; off >= 1; off >>= 1)
      s += __shfl_down(s, off, 64);
    if (lane == 0) wsum[wid] = s;
    __syncthreads();
    if (threadIdx.x == 0)
      out[0] = (wsum[0] + wsum[1] + wsum[2] + wsum[3]) / (float)batch;
  }
}

extern "C" void kernel_launch(void* const* d_in, const int* in_sizes, int n_in,
                              void* d_out, int out_size, void* d_ws, size_t ws_size,
                              hipStream_t stream) {
  const float* a_ry = (const float*)d_in[0];
  const float* a_rz = (const float*)d_in[1];
  const float* p_ry = (const float*)d_in[2];
  const float* p_rz = (const float*)d_in[3];
  const float* n_ry = (const float*)d_in[4];
  const float* n_rz = (const float*)d_in[5];
  float* out = (float*)d_out;

  const int batch = in_sizes[0] / 8;            // NL*NQ = 8 angles per element
  const int nblocks = (batch + 255) / 256;      // 2048

  float* partials = (float*)d_ws;
  unsigned* counter = (unsigned*)((char*)d_ws + (size_t)nblocks * sizeof(float));

  hipMemsetAsync(counter, 0, sizeof(unsigned), stream);  // captured into the graph

  triplet_fused<<<nblocks, 256, 0, stream>>>(a_ry, a_rz, p_ry, p_rz, n_ry, n_rz,
                                             partials, counter, out, batch);
}

// Round 6
// 29.168 us; speedup vs baseline: 2.9852x; 2.9852x over previous
//
#include <hip/hip_runtime.h>

typedef float v2f __attribute__((ext_vector_type(2)));

constexpr int NQ = 4;
constexpr int DIM = 16;          // 2^NQ
constexpr float MARGIN = 0.3f;
constexpr float INV2PI = 0.15915494309189535f;

__device__ __forceinline__ v2f mk2(float x, float y) { v2f r; r.x = x; r.y = y; return r; }

// complex multiply a*b where bs = {-b.y, b.x} is precomputed.
__device__ __forceinline__ v2f cmul_pre(v2f a, v2f b, v2f bs) {
  return a.xx * b + a.yy * bs;
}

__device__ __forceinline__ void sincos_hw(float rev, float& s, float& c) {
  s = __builtin_amdgcn_sinf(rev);   // input in revolutions
  c = __builtin_amdgcn_cosf(rev);
}

// CNOT ladder CNOT(q,q+1), q=0..2; qubit q == flat bit (3-q). Free permutation.
__device__ __forceinline__ void cnot_ladder(v2f s[DIM]) {
#pragma unroll
  for (int q = 0; q < NQ - 1; ++q) {
    const int pc = 1 << (NQ - 1 - q);
    const int pt = 1 << (NQ - 2 - q);
#pragma unroll
    for (int i = 0; i < DIM; ++i) {
      if ((i & pc) && !(i & pt)) {
        const int j = i | pt;
        v2f t = s[i]; s[i] = s[j]; s[j] = t;
      }
    }
  }
}

// Layer-1 product state (RZ as diag(1,e^{i z}), global phase dropped) + CNOT
// ladder + layer-2 RY butterflies. Final RZ layer is merged into the overlap
// (delta angles); final CNOT ladder cancels in the overlap.
__device__ __forceinline__ void sim_core(const float ry[8], const float rz[8], v2f s[DIM]) {
  float c0[NQ]; v2f p1[NQ], p1s[NQ];
#pragma unroll
  for (int q = 0; q < NQ; ++q) {
    float sy, cy; sincos_hw(ry[q] * (0.5f * INV2PI), sy, cy);
    float sz, cz; sincos_hw(rz[q] * INV2PI, sz, cz);
    c0[q]  = cy;
    p1[q]  = mk2(sy * cz, sy * sz);
    p1s[q] = mk2(-p1[q].y, p1[q].x);
  }
  // tensor-product tree; qubit q is flat bit (3-q)
  v2f t2[4];
  t2[0] = mk2(c0[0] * c0[1], 0.0f);
  t2[1] = c0[0] * p1[1];
  t2[2] = c0[1] * p1[0];
  t2[3] = cmul_pre(p1[0], p1[1], p1s[1]);
  v2f t3[8];
#pragma unroll
  for (int k = 0; k < 4; ++k) {
    t3[2*k]   = t2[k] * c0[2];
    t3[2*k+1] = cmul_pre(t2[k], p1[2], p1s[2]);
  }
#pragma unroll
  for (int k = 0; k < 8; ++k) {
    s[2*k]   = t3[k] * c0[3];
    s[2*k+1] = cmul_pre(t3[k], p1[3], p1s[3]);
  }

  cnot_ladder(s);

  // layer-2 RY butterflies
#pragma unroll
  for (int q = 0; q < NQ; ++q) {
    const int bit = 1 << (NQ - 1 - q);
    float sy, cy; sincos_hw(ry[4 + q] * (0.5f * INV2PI), sy, cy);
#pragma unroll
    for (int i = 0; i < DIM; ++i) {
      if (i & bit) continue;
      const int j = i | bit;
      const v2f a0 = s[i], a1 = s[j];
      s[i] = cy * a0 - sy * a1;
      s[j] = sy * a0 + cy * a1;
    }
  }
}

// Merged final RZ (delta angles dz[q] = z[q] - za[q]) then |<a|x>|^2.
__device__ __forceinline__ float fid_with_dz(const v2f a[DIM], v2f x[DIM], const float dz[NQ]) {
#pragma unroll
  for (int q = 0; q < NQ; ++q) {
    const int bit = 1 << (NQ - 1 - q);
    float sz, cz; sincos_hw(dz[q] * INV2PI, sz, cz);
    const v2f ph  = mk2(cz, sz);
    const v2f phs = mk2(-sz, cz);
#pragma unroll
    for (int i = 0; i < DIM; ++i) {
      if (i & bit) x[i] = cmul_pre(x[i], ph, phs);
    }
  }
  v2f ov1 = mk2(0.f, 0.f), ov2 = mk2(0.f, 0.f);
#pragma unroll
  for (int i = 0; i < DIM; ++i) {
    ov1 += a[i].xx * x[i];      // {Σ ar*xr, Σ ar*xi}
    ov2 += a[i].yy * x[i].yx;   // {Σ ai*xi, Σ ai*xr}
  }
  const float ovr = ov1.x + ov2.x;
  const float ovi = ov1.y - ov2.y;
  return ovr * ovr + ovi * ovi;
}

__device__ __forceinline__ void load8(const float* __restrict__ p, int b, float a[8]) {
  const float4* v = reinterpret_cast<const float4*>(p) + (size_t)b * 2;
  float4 x0 = v[0], x1 = v[1];
  a[0]=x0.x; a[1]=x0.y; a[2]=x0.z; a[3]=x0.w;
  a[4]=x1.x; a[5]=x1.y; a[6]=x1.z; a[7]=x1.w;
}

__global__ __launch_bounds__(256) void triplet_main(
    const float* __restrict__ a_ry, const float* __restrict__ a_rz,
    const float* __restrict__ p_ry, const float* __restrict__ p_rz,
    const float* __restrict__ n_ry, const float* __restrict__ n_rz,
    float* __restrict__ block_sums, int batch) {
  const int b = blockIdx.x * blockDim.x + threadIdx.x;

  float loss = 0.0f;
  if (b < batch) {
    float ry[8], rz[8], arz2[NQ];

    // anchor (final RZ merged into the dots, final CNOT ladder cancelled)
    load8(a_ry, b, ry); load8(a_rz, b, rz);
#pragma unroll
    for (int q = 0; q < NQ; ++q) arz2[q] = rz[4 + q];
    v2f as[DIM];
    sim_core(ry, rz, as);

    // positive
    load8(p_ry, b, ry); load8(p_rz, b, rz);
    v2f xs[DIM];
    sim_core(ry, rz, xs);
    float dz[NQ];
#pragma unroll
    for (int q = 0; q < NQ; ++q) dz[q] = rz[4 + q] - arz2[q];
    const float fid_pos = fid_with_dz(as, xs, dz);

    // negative (reuse xs)
    load8(n_ry, b, ry); load8(n_rz, b, rz);
    sim_core(ry, rz, xs);
#pragma unroll
    for (int q = 0; q < NQ; ++q) dz[q] = rz[4 + q] - arz2[q];
    const float fid_neg = fid_with_dz(as, xs, dz);

    loss = fmaxf(MARGIN - fid_pos + fid_neg, 0.0f);
  }

  // wave (64) reduce, then LDS across the 4 waves
#pragma unroll
  for (int off = 32; off >= 1; off >>= 1)
    loss += __shfl_down(loss, off, 64);

  __shared__ float wsum[4];
  const int lane = threadIdx.x & 63;
  const int wid  = threadIdx.x >> 6;
  if (lane == 0) wsum[wid] = loss;
  __syncthreads();
  if (threadIdx.x == 0) {
    block_sums[blockIdx.x] = wsum[0] + wsum[1] + wsum[2] + wsum[3];
  }
}

__global__ __launch_bounds__(256) void triplet_reduce(
    const float* __restrict__ block_sums, int nblocks, float* __restrict__ out, float inv_batch) {
  float s = 0.0f;
  for (int i = threadIdx.x; i < nblocks; i += 256) s += block_sums[i];
#pragma unroll
  for (int off = 32; off >= 1; off >>= 1)
    s += __shfl_down(s, off, 64);

  __shared__ float wsum[4];
  const int lane = threadIdx.x & 63;
  const int wid  = threadIdx.x >> 6;
  if (lane == 0) wsum[wid] = s;
  __syncthreads();
  if (threadIdx.x == 0) {
    out[0] = (wsum[0] + wsum[1] + wsum[2] + wsum[3]) * inv_batch;
  }
}

extern "C" void kernel_launch(void* const* d_in, const int* in_sizes, int n_in,
                              void* d_out, int out_size, void* d_ws, size_t ws_size,
                              hipStream_t stream) {
  const float* a_ry = (const float*)d_in[0];
  const float* a_rz = (const float*)d_in[1];
  const float* p_ry = (const float*)d_in[2];
  const float* p_rz = (const float*)d_in[3];
  const float* n_ry = (const float*)d_in[4];
  const float* n_rz = (const float*)d_in[5];
  float* out = (float*)d_out;

  const int batch = in_sizes[0] / 8;            // NL*NQ = 8 angles per element
  const int nblocks = (batch + 255) / 256;      // 2048
  float* block_sums = (float*)d_ws;

  triplet_main<<<nblocks, 256, 0, stream>>>(a_ry, a_rz, p_ry, p_rz, n_ry, n_rz,
                                            block_sums, batch);
  triplet_reduce<<<1, 256, 0, stream>>>(block_sums, nblocks, out, 1.0f / (float)batch);
}